// Round 1
// 411.369 us; speedup vs baseline: 1.2066x; 1.2066x over previous
//
#include <hip/hip_runtime.h>
#include <math.h>

#define N_NODES 50000
#define N_EDGES 400000
#define F_DIM   128
#define N_RBF   20
#define SCAN_B  256
#define N_CHUNK ((N_NODES + SCAN_B - 1) / SCAN_B)   // 196

// ---------------------------------------------------------------------------
// phi_table[t] = silu(emb_table[t] @ w_phi1 + b_phi1) @ w_phi2 + b_phi2
// ---------------------------------------------------------------------------
__global__ void phi_table_kernel(const float* __restrict__ emb_table,
                                 const float* __restrict__ w_phi1,
                                 const float* __restrict__ b_phi1,
                                 const float* __restrict__ w_phi2,
                                 const float* __restrict__ b_phi2,
                                 float* __restrict__ phi_table) {
    __shared__ float emb_s[F_DIM];
    __shared__ float h_s[F_DIM];
    const int t = blockIdx.x;
    const int o = threadIdx.x;
    if (o < F_DIM) emb_s[o] = emb_table[t * F_DIM + o];
    __syncthreads();
    if (o < F_DIM) {
        float acc = b_phi1[o];
#pragma unroll 8
        for (int k = 0; k < F_DIM; ++k)
            acc = fmaf(emb_s[k], w_phi1[k * F_DIM + o], acc);
        h_s[o] = acc / (1.0f + expf(-acc));   // silu
    }
    __syncthreads();
    float a2 = b_phi2[o];
#pragma unroll 8
    for (int k = 0; k < F_DIM; ++k)
        a2 = fmaf(h_s[k], w_phi2[k * (3 * F_DIM) + o], a2);
    phi_table[t * (3 * F_DIM) + o] = a2;
}

__global__ void count_kernel(const int* __restrict__ edst, int* __restrict__ counts) {
    const int e = blockIdx.x * blockDim.x + threadIdx.x;
    if (e < N_EDGES) atomicAdd(&counts[edst[e]], 1);
}

__global__ void scan_partial_kernel(const int* __restrict__ counts,
                                    int* __restrict__ partial,
                                    int* __restrict__ chunk_sums) {
    __shared__ int s[SCAN_B];
    const int tid = threadIdx.x;
    const int gid = blockIdx.x * SCAN_B + tid;
    const int v = (gid < N_NODES) ? counts[gid] : 0;
    s[tid] = v;
    __syncthreads();
    for (int d = 1; d < SCAN_B; d <<= 1) {
        const int t = (tid >= d) ? s[tid - d] : 0;
        __syncthreads();
        s[tid] += t;
        __syncthreads();
    }
    if (gid < N_NODES) partial[gid] = s[tid] - v;
    if (tid == SCAN_B - 1) chunk_sums[blockIdx.x] = s[tid];
}

__global__ void scan_sums_kernel(int* __restrict__ chunk_sums,
                                 int* __restrict__ chunk_pref) {
    __shared__ int s[SCAN_B];
    const int tid = threadIdx.x;
    const int v = (tid < N_CHUNK) ? chunk_sums[tid] : 0;
    s[tid] = v;
    __syncthreads();
    for (int d = 1; d < SCAN_B; d <<= 1) {
        const int t = (tid >= d) ? s[tid - d] : 0;
        __syncthreads();
        s[tid] += t;
        __syncthreads();
    }
    if (tid < N_CHUNK) chunk_pref[tid] = s[tid] - v;
}

__global__ void finalize_offsets_kernel(const int* __restrict__ partial,
                                        const int* __restrict__ chunk_pref,
                                        int* __restrict__ offsets,
                                        int* __restrict__ cursor) {
    const int i = blockIdx.x * blockDim.x + threadIdx.x;
    if (i >= N_NODES) return;
    const int o = partial[i] + chunk_pref[i >> 8];
    offsets[i] = o;
    cursor[i]  = o;
}

// ---------------------------------------------------------------------------
// Edge-parallel precompute + CSR fill. Per edge, one 32B record at slot p:
//   rec[2p]   = (px, py, pz, d)
//   rec[2p+1] = (j, t, sin(a)/d, 2*cos(a))   [a = pi*d/5]
// ---------------------------------------------------------------------------
__global__ void edge_pre_kernel(const float* __restrict__ pos,
                                const int* __restrict__ z,
                                const int* __restrict__ esrc,
                                const int* __restrict__ edst,
                                int* __restrict__ cursor,
                                float4* __restrict__ rec) {
    const int e = blockIdx.x * blockDim.x + threadIdx.x;
    if (e >= N_EDGES) return;
    const int j = esrc[e];
    const int i = edst[e];
    const int p = atomicAdd(&cursor[i], 1);

    const float px = pos[3 * i + 0] - pos[3 * j + 0];
    const float py = pos[3 * i + 1] - pos[3 * j + 1];
    const float pz = pos[3 * i + 2] - pos[3 * j + 2];
    const float d = sqrtf(px * px + py * py + pz * pz);
    const float inv_d = 1.0f / d;

    float sa, ca;
    sincosf(0.6283185307179586f * d, &sa, &ca);   // pi*d/5

    rec[2 * p] = make_float4(px, py, pz, d);
    float4 b;
    b.x = __int_as_float(j);
    b.y = __int_as_float(z[j]);
    b.z = sa * inv_d;
    b.w = 2.0f * ca;
    rec[2 * p + 1] = b;
}

// ---------------------------------------------------------------------------
// Gather: 128-thread group per node (2/block). Thread f owns outputs
// f, 128+f, 256+f.
//
// __launch_bounds__(256, 2): raise the VGPR cap to 256 so the 60 w_rbf
// columns are ACTUALLY register-resident (previous build capped at 60 VGPR ->
// compiler sank ~60 weight loads into the inner loop).
//
// 2-deep software pipeline with clamped (branch-free) indices: at iter k we
// issue rec[k+2] and the eq/phi gathers for k+1 (whose rec arrived an
// iteration ago), while computing edge k. Breaks the serial rec->eq load
// chain; every load gets a full iteration of compute (x resident waves) to
// land.
// ---------------------------------------------------------------------------
__global__ void __launch_bounds__(256, 2)
gather_kernel(const float* __restrict__ eq,
              const float* __restrict__ emb_table,
              const float* __restrict__ phi_table,
              const float* __restrict__ w_rbf,
              const float* __restrict__ b_rbf,
              const int* __restrict__ z,
              const float4* __restrict__ rec,
              const int* __restrict__ offsets,
              const int* __restrict__ counts,
              float* __restrict__ out_emb,
              float* __restrict__ out_eq) {
    const int tid = threadIdx.x;
    const int grp = tid >> 7;
    const int f   = tid & 127;
    const int i   = blockIdx.x * 2 + grp;
    if (i >= N_NODES) return;

    const int start = offsets[i];
    const int cnt   = counts[i];

    // loop-invariant weights -> registers (60 loads, once)
    float w1r[N_RBF], w2r[N_RBF], w3r[N_RBF];
#pragma unroll
    for (int n = 0; n < N_RBF; ++n) {
        const float* wr = w_rbf + n * (3 * F_DIM);
        w1r[n] = wr[f];
        w2r[n] = wr[F_DIM + f];
        w3r[n] = wr[2 * F_DIM + f];
    }
    const float br1 = b_rbf[f];
    const float br2 = b_rbf[F_DIM + f];
    const float br3 = b_rbf[2 * F_DIM + f];

    float accE = 0.f, ax = 0.f, ay = 0.f, az = 0.f;

    if (cnt > 0) {
        const int last = cnt - 1;
        const float* eqf = eq + (size_t)f * 3;           // + j*384 per edge
        const float* ptf = phi_table + f;                 // + t*384 per edge

        // ---- prologue: stage 0 fully loaded, stage 1 rec loaded ----
        float4 A0 = rec[2 * start];
        float4 B0 = rec[2 * start + 1];
        const int p1 = start + min(1, last);
        float4 A1 = rec[2 * p1];
        float4 B1 = rec[2 * p1 + 1];
        {
            const int j0 = __float_as_int(B0.x);
            const int t0 = __float_as_int(B0.y);
            const float* ej = eqf + (size_t)j0 * (F_DIM * 3);
            const float* pt = ptf + t0 * (3 * F_DIM);
            // fall through into loop with these in regs
            float e0 = ej[0], e1 = ej[1], e2 = ej[2];
            float p0 = pt[0], p1v = pt[F_DIM], p2v = pt[2 * F_DIM];

            float eq0 = e0, eq1 = e1, eq2 = e2;
            float ph0 = p0, ph1 = p1v, ph2 = p2v;

            for (int k = 0; k < cnt; ++k) {
                // stage A: issue rec load for k+2 (clamped -> no branch)
                const int p2 = start + min(k + 2, last);
                const float4 A2 = rec[2 * p2];
                const float4 B2 = rec[2 * p2 + 1];

                // stage B: issue eq/phi gathers for k+1 (rec already here)
                const int j1 = __float_as_int(B1.x);
                const int t1 = __float_as_int(B1.y);
                const float* ej1 = eqf + (size_t)j1 * (F_DIM * 3);
                const float* pt1 = ptf + t1 * (3 * F_DIM);
                const float neq0 = ej1[0], neq1 = ej1[1], neq2 = ej1[2];
                const float nph0 = pt1[0], nph1 = pt1[F_DIM], nph2 = pt1[2 * F_DIM];

                // ---- pure-VALU compute for edge k ----
                float W1 = br1, W2 = br2, W3 = br3;
                float tm1 = 0.0f, tc = B0.z;
                const float twoc = B0.w;
#pragma unroll
                for (int n = 0; n < N_RBF; ++n) {
                    W1 = fmaf(tc, w1r[n], W1);
                    W2 = fmaf(tc, w2r[n], W2);
                    W3 = fmaf(tc, w3r[n], W3);
                    const float tn = fmaf(twoc, tc, -tm1);
                    tm1 = tc; tc = tn;
                }
                accE += ph0 * W1;
                const float s2 = ph1 * W2;
                const float s3 = ph2 * W3 * A0.w;
                ax = fmaf(eq0, s2, fmaf(s3, A0.x, ax));
                ay = fmaf(eq1, s2, fmaf(s3, A0.y, ay));
                az = fmaf(eq2, s2, fmaf(s3, A0.z, az));

                // rotate pipeline
                A0 = A1; B0 = B1; A1 = A2; B1 = B2;
                eq0 = neq0; eq1 = neq1; eq2 = neq2;
                ph0 = nph0; ph1 = nph1; ph2 = nph2;
            }
        }
    }

    out_emb[(size_t)i * F_DIM + f] = emb_table[z[i] * F_DIM + f] + accE;

    const float* ei = eq     + ((size_t)i * F_DIM + f) * 3;
    float*       od = out_eq + ((size_t)i * F_DIM + f) * 3;
    od[0] = ei[0] + ax;
    od[1] = ei[1] + ay;
    od[2] = ei[2] + az;
}

// ---------------------------------------------------------------------------
extern "C" void kernel_launch(void* const* d_in, const int* in_sizes, int n_in,
                              void* d_out, int out_size, void* d_ws, size_t ws_size,
                              hipStream_t stream) {
    const float* pos       = (const float*)d_in[0];
    const float* eq        = (const float*)d_in[1];
    const float* emb_table = (const float*)d_in[2];
    const float* w_phi1    = (const float*)d_in[3];
    const float* b_phi1    = (const float*)d_in[4];
    const float* w_phi2    = (const float*)d_in[5];
    const float* b_phi2    = (const float*)d_in[6];
    const float* w_rbf     = (const float*)d_in[7];
    const float* b_rbf     = (const float*)d_in[8];
    const int*   z         = (const int*)d_in[9];
    const int*   esrc      = (const int*)d_in[10];
    const int*   edst      = (const int*)d_in[11];

    float* out_emb = (float*)d_out;                               // [N, F]
    float* out_eq  = (float*)d_out + (size_t)N_NODES * F_DIM;     // [N, F, 3]

    // workspace layout (16B-aligned chunks)
    char* ws = (char*)d_ws;
    float4* rec        = (float4*)ws;  ws += (size_t)N_EDGES * 32;
    float*  phi_table  = (float*)ws;   ws += 100 * 3 * F_DIM * 4;
    int*    counts     = (int*)ws;     ws += N_NODES * 4;
    int*    partial    = (int*)ws;     ws += N_NODES * 4;
    int*    offsets    = (int*)ws;     ws += N_NODES * 4;
    int*    cursor     = (int*)ws;     ws += N_NODES * 4;
    int*    chunk_sums = (int*)ws;     ws += SCAN_B * 4;
    int*    chunk_pref = (int*)ws;     ws += SCAN_B * 4;

    hipMemsetAsync(counts, 0, N_NODES * sizeof(int), stream);
    phi_table_kernel<<<100, 3 * F_DIM, 0, stream>>>(emb_table, w_phi1, b_phi1,
                                                    w_phi2, b_phi2, phi_table);
    count_kernel<<<(N_EDGES + 255) / 256, 256, 0, stream>>>(edst, counts);
    scan_partial_kernel<<<N_CHUNK, SCAN_B, 0, stream>>>(counts, partial, chunk_sums);
    scan_sums_kernel<<<1, SCAN_B, 0, stream>>>(chunk_sums, chunk_pref);
    finalize_offsets_kernel<<<(N_NODES + 255) / 256, 256, 0, stream>>>(
        partial, chunk_pref, offsets, cursor);
    edge_pre_kernel<<<(N_EDGES + 255) / 256, 256, 0, stream>>>(
        pos, z, esrc, edst, cursor, rec);
    gather_kernel<<<(N_NODES + 1) / 2, 256, 0, stream>>>(
        eq, emb_table, phi_table, w_rbf, b_rbf, z, rec,
        offsets, counts, out_emb, out_eq);
}